// Round 5
// baseline (800.294 us; speedup 1.0000x reference)
//
#include <hip/hip_runtime.h>
#include <math.h>

// MultiScaleTransformerGSM on MI355X (gfx950).
// LN+ReLU(+bf16 x copy) -> per branch: dwconv -> gate GEMM -> proj1 GEMM
// (A-staging gathers shifted fusion) -> proj2 GEMM + residual.
// GEMM: 128x256 tile, BK=32, global_load_lds staging, 4 waves x (64x128).

#define MROWS 25216   // B*T*N = 8*16*197
#define CD    768
#define NTOK  197
#define TFR   16

typedef __attribute__((ext_vector_type(8))) short short8;
typedef __attribute__((ext_vector_type(4))) float floatx4;
typedef unsigned int u32;

__device__ __forceinline__ unsigned short f2bf(float f) {
    union { float f; unsigned u; } v; v.f = f;
    unsigned r = v.u + 0x7FFFu + ((v.u >> 16) & 1u);
    return (unsigned short)(r >> 16);
}
__device__ __forceinline__ float bf2f(unsigned short h) {
    union { unsigned u; float f; } v; v.u = ((unsigned)h) << 16;
    return v.f;
}

// async global->LDS, 16B per lane; LDS dest = wave-uniform base + lane*16
__device__ __forceinline__ void gl2lds16(const void* g, void* l) {
    __builtin_amdgcn_global_load_lds(
        (__attribute__((address_space(1))) void*)(unsigned long long)g,
        (__attribute__((address_space(3))) void*)(u32)(unsigned long long)l,
        16, 0, 0);
}

// ---------------- LayerNorm + ReLU -> bf16 (also emits bf16 copy of x) ----------------
__global__ __launch_bounds__(256)
void ln_relu_kernel(const float* __restrict__ x, const float* __restrict__ g,
                    const float* __restrict__ b, unsigned short* __restrict__ xn,
                    unsigned short* __restrict__ xb) {
    int row = blockIdx.x;
    int tid = threadIdx.x;
    const float* xr = x + (size_t)row * CD;
    float v0 = xr[tid], v1 = xr[tid + 256], v2 = xr[tid + 512];
    float s = v0 + v1 + v2;
    __shared__ float red[8];
#pragma unroll
    for (int off = 32; off; off >>= 1) s += __shfl_down(s, off, 64);
    int lane = tid & 63, w = tid >> 6;
    if (lane == 0) red[w] = s;
    __syncthreads();
    float mean = (red[0] + red[1] + red[2] + red[3]) * (1.0f / CD);
    float d0 = v0 - mean, d1 = v1 - mean, d2 = v2 - mean;
    float s2 = d0 * d0 + d1 * d1 + d2 * d2;
#pragma unroll
    for (int off = 32; off; off >>= 1) s2 += __shfl_down(s2, off, 64);
    if (lane == 0) red[4 + w] = s2;
    __syncthreads();
    float var = (red[4] + red[5] + red[6] + red[7]) * (1.0f / CD);
    float inv = rsqrtf(var + 1e-5f);
    unsigned short* xo = xn + (size_t)row * CD;
    unsigned short* xc = xb + (size_t)row * CD;
    float o0 = fmaxf(d0 * inv * g[tid]       + b[tid],       0.0f);
    float o1 = fmaxf(d1 * inv * g[tid + 256] + b[tid + 256], 0.0f);
    float o2 = fmaxf(d2 * inv * g[tid + 512] + b[tid + 512], 0.0f);
    xo[tid] = f2bf(o0); xo[tid + 256] = f2bf(o1); xo[tid + 512] = f2bf(o2);
    xc[tid] = f2bf(v0); xc[tid + 256] = f2bf(v1); xc[tid + 512] = f2bf(v2);
}

// ---------------- Depthwise conv over T, full-T register blocking ----------------
template <int D>
__global__ __launch_bounds__(256)
void dwconv_kernel(const unsigned short* __restrict__ xn, const float* __restrict__ cw,
                   const float* __restrict__ cb, unsigned short* __restrict__ feat) {
    constexpr int KK = 2 * D + 1;
    int gid = blockIdx.x * 256 + threadIdx.x;     // 591*256 exact
    int bn = gid / 96;
    int cg = gid - bn * 96;
    int c0 = cg * 8;
    int b = bn / NTOK;
    size_t base = ((size_t)b * TFR * NTOK + (bn - b * NTOK)) * CD + c0;
    const size_t tstride = (size_t)NTOK * CD;

    short8 u[TFR];
#pragma unroll
    for (int t = 0; t < TFR; ++t)
        u[t] = *(const short8*)(xn + base + (size_t)t * tstride);

    float wgt[8][KK], bb[8];
#pragma unroll
    for (int q = 0; q < 8; ++q) {
        bb[q] = cb[c0 + q];
#pragma unroll
        for (int j = 0; j < KK; ++j) wgt[q][j] = cw[(c0 + q) * KK + j];
    }

#pragma unroll
    for (int t = 0; t < TFR; ++t) {
        float acc[8];
#pragma unroll
        for (int q = 0; q < 8; ++q) acc[q] = bb[q];
#pragma unroll
        for (int j = 0; j < KK; ++j) {
            int tj = t + j - D;
            if (tj < 0 || tj >= TFR) continue;   // compile-time (t,j unrolled)
#pragma unroll
            for (int q = 0; q < 8; ++q)
                acc[q] += bf2f((unsigned short)u[tj][q]) * wgt[q][j];
        }
        short8 o;
#pragma unroll
        for (int q = 0; q < 8; ++q) o[q] = (short)f2bf(acc[q]);
        *(short8*)(feat + base + (size_t)t * tstride) = o;
    }
}

// ---------------- weight transpose+convert: wt[n][k] = bf16(w[k][n]) ----------------
__global__ __launch_bounds__(256)
void wprep3_kernel(const float* __restrict__ w0, const float* __restrict__ w1,
                   const float* __restrict__ w2, unsigned short* __restrict__ t0,
                   unsigned short* __restrict__ t1, unsigned short* __restrict__ t2) {
    const float* w = blockIdx.y == 0 ? w0 : blockIdx.y == 1 ? w1 : w2;
    unsigned short* wt = blockIdx.y == 0 ? t0 : blockIdx.y == 1 ? t1 : t2;
    int gid = blockIdx.x * 256 + threadIdx.x;
    int n = gid / CD, k = gid - n * CD;
    wt[gid] = f2bf(w[(size_t)k * CD + n]);
}

// ---------------- 128x256-tile bf16 MFMA GEMM, global_load_lds staging ----------------
// 4 waves; wave -> (wm = (wave>>1)*64, wn = (wave&1)*128); per wave 4x8 acc tiles.
// EPI 0: gate  -> pure write bf16( wd * sigmoid(v) * xb )
// EPI 1: proj1 -> A-staging gathers shifted fusion of g1,g2,g3; gelu -> bf16
// EPI 2: proj2 -> v + bf16(x) -> fp32 out
// LDS chunk layout (unpadded, required by global_load_lds): chunk q = 16 rows,
// lane i lands at q*1024 + i*16 bytes = row q*16+i/4, shorts (i%4)*8.
template <int EPI>
__global__ __launch_bounds__(256, 2)
void gemm_kernel(const unsigned short* __restrict__ A,
                 const unsigned short* __restrict__ Bt,   // 768x768 bf16, N-major
                 const float* __restrict__ bias,
                 const unsigned short* __restrict__ xb,
                 const unsigned short* __restrict__ g1,
                 const unsigned short* __restrict__ g2,
                 const unsigned short* __restrict__ g3,
                 float* __restrict__ outf,
                 unsigned short* __restrict__ outh,
                 const float* __restrict__ fw,
                 int widx) {
    __shared__ unsigned short As[128 * 32];   //  8 KB
    __shared__ unsigned short Bs[256 * 32];   // 16 KB
    int tid  = threadIdx.x;
    int m0   = blockIdx.x * 128;   // m fastest: consecutive blocks share B n-slice
    int n0   = blockIdx.y * 256;
    int wave = tid >> 6, lane = tid & 63;
    int wm   = (wave >> 1) * 64, wn = (wave & 1) * 128;
    int quad = lane >> 4, l16 = lane & 15;
    int r4   = lane >> 2;          // 0..15: row within chunk
    int ck   = (lane & 3) * 8;     // k-offset (shorts)

    floatx4 acc[4][8];
#pragma unroll
    for (int i = 0; i < 4; ++i)
#pragma unroll
        for (int j = 0; j < 8; ++j) acc[i][j] = (floatx4){0.f, 0.f, 0.f, 0.f};

    for (int kt = 0; kt < CD; kt += 32) {
        __syncthreads();
        // A: 8 chunks (128 rows)
#pragma unroll
        for (int h = 0; h < 2; ++h) {
            int q   = wave + h * 4;
            int row = q * 16 + r4;
            if (EPI == 1) {
                // gather fused[m][kk] = sum_d shifted y_d (softmax weights pre-folded)
                int m  = m0 + row;
                int t  = (m / NTOK) & 15;
                int kk = kt + ck;
                float vals[8] = {0.f, 0.f, 0.f, 0.f, 0.f, 0.f, 0.f, 0.f};
                const unsigned short* ybs[3] = {g1, g2, g3};
#pragma unroll
                for (int d = 1; d <= 3; ++d) {
                    int src; bool ok;
                    if (kk < 256)      { src = m + d * NTOK; ok = (t + d) < TFR; }
                    else if (kk < 512) { src = m - d * NTOK; ok = (t - d) >= 0; }
                    else               { src = m;            ok = true; }
                    if (ok) {
                        short8 u = *(const short8*)(ybs[d - 1] + (size_t)src * CD + kk);
#pragma unroll
                        for (int e = 0; e < 8; ++e) vals[e] += bf2f((unsigned short)u[e]);
                    }
                }
                short8 o;
#pragma unroll
                for (int e = 0; e < 8; ++e) o[e] = (short)f2bf(vals[e]);
                *(short8*)(&As[q * 512 + lane * 8]) = o;
            } else {
                gl2lds16(A + (size_t)(m0 + row) * CD + kt + ck, &As[q * 512]);
            }
        }
        // B: 16 chunks (256 rows)
#pragma unroll
        for (int h = 0; h < 4; ++h) {
            int q   = wave + h * 4;
            int row = q * 16 + r4;
            gl2lds16(Bt + (size_t)(n0 + row) * CD + kt + ck, &Bs[q * 512]);
        }
        __syncthreads();
        short8 af[4], bfr[8];
#pragma unroll
        for (int i = 0; i < 4; ++i) af[i]  = *(const short8*)(&As[(wm + i * 16 + l16) * 32 + quad * 8]);
#pragma unroll
        for (int j = 0; j < 8; ++j) bfr[j] = *(const short8*)(&Bs[(wn + j * 16 + l16) * 32 + quad * 8]);
#pragma unroll
        for (int i = 0; i < 4; ++i)
#pragma unroll
            for (int j = 0; j < 8; ++j)
                acc[i][j] = __builtin_amdgcn_mfma_f32_16x16x32_bf16(af[i], bfr[j], acc[i][j], 0, 0, 0);
    }

    float wd = 0.f;
    if (EPI == 0) {
        float f0 = fw[0], f1 = fw[1], f2 = fw[2];
        float mx = fmaxf(f0, fmaxf(f1, f2));
        float e0 = expf(f0 - mx), e1 = expf(f1 - mx), e2 = expf(f2 - mx);
        float inv = 1.f / (e0 + e1 + e2);
        wd = (widx == 0 ? e0 : widx == 1 ? e1 : e2) * inv;
    }

#pragma unroll
    for (int j = 0; j < 8; ++j) {
        int col = n0 + wn + j * 16 + l16;
        float bc = bias[col];
#pragma unroll
        for (int i = 0; i < 4; ++i) {
#pragma unroll
            for (int r = 0; r < 4; ++r) {
                int row = m0 + wm + i * 16 + quad * 4 + r;   // C/D: col=lane&15, row=quad*4+reg
                size_t idx = (size_t)row * CD + col;
                float v = acc[i][j][r] + bc;
                if (EPI == 0) {
                    float gte = 1.f / (1.f + expf(-v));
                    outh[idx] = f2bf(wd * gte * bf2f(xb[idx]));
                } else if (EPI == 1) {
                    float gl = 0.5f * v * (1.0f + erff(v * 0.70710678118f));
                    outh[idx] = f2bf(gl);
                } else {
                    outf[idx] = v + bf2f(xb[idx]);
                }
            }
        }
    }
}

extern "C" void kernel_launch(void* const* d_in, const int* in_sizes, int n_in,
                              void* d_out, int out_size, void* d_ws, size_t ws_size,
                              hipStream_t stream) {
    const float* x      = (const float*)d_in[0];
    const float* ln_g   = (const float*)d_in[1];
    const float* ln_b   = (const float*)d_in[2];
    const float* gate_w = (const float*)d_in[3];
    const float* gate_b = (const float*)d_in[4];
    const float* pw1    = (const float*)d_in[5];
    const float* pb1    = (const float*)d_in[6];
    const float* pw2    = (const float*)d_in[7];
    const float* pb2    = (const float*)d_in[8];
    const float* fw     = (const float*)d_in[9];
    const float* cw[3]  = {(const float*)d_in[11], (const float*)d_in[13], (const float*)d_in[15]};
    const float* cb[3]  = {(const float*)d_in[12], (const float*)d_in[14], (const float*)d_in[16]};

    char* ws = (char*)d_ws;
    const size_t SB = (size_t)MROWS * CD * 2;                   // 38,731,776
    unsigned short* gwt  = (unsigned short*)(ws + 0);
    unsigned short* p1t  = (unsigned short*)(ws + 1179648);
    unsigned short* p2t  = (unsigned short*)(ws + 2359296);
    unsigned short* xn   = (unsigned short*)(ws + 3538944);
    unsigned short* xb   = (unsigned short*)(ws + 3538944 + SB);
    unsigned short* feat = (unsigned short*)(ws + 3538944 + 2 * SB);
    unsigned short* y1   = (unsigned short*)(ws + 3538944 + 3 * SB);
    unsigned short* y2   = (unsigned short*)(ws + 3538944 + 4 * SB);
    unsigned short* y3   = (unsigned short*)(ws + 3538944 + 5 * SB);
    unsigned short* h1   = feat;   // feat dead after last gate GEMM
    // total: 3,538,944 + 6*SB = 235,929,600 bytes

    dim3 wg(2304, 3);
    wprep3_kernel<<<wg, 256, 0, stream>>>(gate_w, pw1, pw2, gwt, p1t, p2t);
    ln_relu_kernel<<<MROWS, 256, 0, stream>>>(x, ln_g, ln_b, xn, xb);

    dim3 gg(197, 3);   // m fastest; n0 = y*256
    dwconv_kernel<1><<<591, 256, 0, stream>>>(xn, cw[0], cb[0], feat);
    gemm_kernel<0><<<gg, 256, 0, stream>>>(feat, gwt, gate_b, xb,
                                           nullptr, nullptr, nullptr, nullptr, y1, fw, 0);
    dwconv_kernel<2><<<591, 256, 0, stream>>>(xn, cw[1], cb[1], feat);
    gemm_kernel<0><<<gg, 256, 0, stream>>>(feat, gwt, gate_b, xb,
                                           nullptr, nullptr, nullptr, nullptr, y2, fw, 1);
    dwconv_kernel<3><<<591, 256, 0, stream>>>(xn, cw[2], cb[2], feat);
    gemm_kernel<0><<<gg, 256, 0, stream>>>(feat, gwt, gate_b, xb,
                                           nullptr, nullptr, nullptr, nullptr, y3, fw, 2);

    gemm_kernel<1><<<gg, 256, 0, stream>>>(nullptr, p1t, pb1, nullptr,
                                           y1, y2, y3, nullptr, h1, nullptr, 0);
    gemm_kernel<2><<<gg, 256, 0, stream>>>(h1, p2t, pb2, xb,
                                           nullptr, nullptr, nullptr, (float*)d_out, nullptr, nullptr, 0);
}